// Round 6
// baseline (347.970 us; speedup 1.0000x reference)
//
#include <hip/hip_runtime.h>
#include <hip/hip_bf16.h>
#include <stdint.h>

#define M_DIM 8192
#define K_DIM 2048
#define N_DIM 4096
#define BT 256
#define NT_M (M_DIM / BT)   // 32 m-tiles
#define NT_N (N_DIM / BT)   // 16 n-tiles
#define NKT (K_DIM / 64)    // 32 K-tiles of BK=64

typedef __hip_bfloat16 bf16;
typedef __attribute__((ext_vector_type(8))) short bf16x8;
typedef __attribute__((ext_vector_type(4))) float floatx4;

__device__ __forceinline__ void gload_lds16(const void* g, void* l) {
  __builtin_amdgcn_global_load_lds((const __attribute__((address_space(1))) void*)g,
                                   (__attribute__((address_space(3))) void*)l, 16, 0, 0);
}

// ---------------- Kernel 0: fp32 -> bf16 convert (x then W), 8 elems/thread ----
__global__ __launch_bounds__(256) void convert_kernel(
    const float* __restrict__ x, const float* __restrict__ W,
    bf16* __restrict__ xb, bf16* __restrict__ wb) {
  int idx = blockIdx.x * 256 + threadIdx.x;
  int e = idx * 8;
  const int NX = M_DIM * K_DIM;  // 16,777,216
  const float* src;
  bf16* dst;
  if (e < NX) { src = x + e; dst = xb + e; }
  else        { src = W + (e - NX); dst = wb + (e - NX); }
  const float4* s4 = (const float4*)src;
  float4 a = s4[0];
  float4 c = s4[1];
  union { bf16 h[8]; uint4 u; } o;
  o.h[0] = __float2bfloat16(a.x); o.h[1] = __float2bfloat16(a.y);
  o.h[2] = __float2bfloat16(a.z); o.h[3] = __float2bfloat16(a.w);
  o.h[4] = __float2bfloat16(c.x); o.h[5] = __float2bfloat16(c.y);
  o.h[6] = __float2bfloat16(c.z); o.h[7] = __float2bfloat16(c.w);
  *(uint4*)dst = o.u;
}

// ---------------- Kernel 1: 256x256 8-phase pipelined GEMM (C^T) + GN + min ----
// Hooked schedule: each phase's ds_reads are issued INSIDE the MFMA cluster
// (after MFMA 4/8/12, sched_barrier-pinned) and consumed TWO phases later, so
// the LDS drain overlaps MFMA execution instead of serializing at the phase
// top. Gates (counted lgkmcnt) 4/8/0/-/4/8/0/-; vmcnt(0) at p3/p7 retires
// loads staged 2 phases earlier. Every LDS overwrite is >=1 barrier after the
// gate that confirms that region's last reads (full hazard matrix audited).

#define BARX() __builtin_amdgcn_s_barrier()
#define SB0()  __builtin_amdgcn_sched_barrier(0)
#define LGKMW(n) do { asm volatile("s_waitcnt lgkmcnt(" n ")" ::: "memory"); \
                      __builtin_amdgcn_sched_barrier(0); } while (0)
#define VMW(n)   do { asm volatile("s_waitcnt vmcnt(" n ")" ::: "memory"); \
                      __builtin_amdgcn_sched_barrier(0); } while (0)

// stage one half-tile (128 rows x 64 k) of one matrix: 2 gload_lds per wave
#define STG2(gp, kt, hh, dp) do { \
  gload_lds16((gp) + ((hh) * 128 + 0) * K_DIM + (kt) * 64, (void*)((dp) + (hh) * 8192)); \
  gload_lds16((gp) + ((hh) * 128 + 8) * K_DIM + (kt) * 64, (void*)((dp) + (hh) * 8192 + 512)); \
} while (0)

// frag read pieces (2 or 4 ds_read_b128 each); swk* carries the XOR swizzle
#define RD_A0_P(rp, i2) \
  af0[i2][0] = *(const bf16x8*)((rp) + ((i2) * 16) * 64 + swk0); \
  af0[i2][1] = *(const bf16x8*)((rp) + ((i2) * 16) * 64 + swk1);
#define RD_A1_P(rp, i2) \
  af1[i2][0] = *(const bf16x8*)((rp) + (64 + (i2) * 16) * 64 + swk0); \
  af1[i2][1] = *(const bf16x8*)((rp) + (64 + (i2) * 16) * 64 + swk1);
#define RD_B01_P(rp, B) \
  B[0][0] = *(const bf16x8*)((rp) + swk0); \
  B[0][1] = *(const bf16x8*)((rp) + swk1); \
  B[1][0] = *(const bf16x8*)((rp) + 16 * 64 + swk0); \
  B[1][1] = *(const bf16x8*)((rp) + 16 * 64 + swk1);
#define RD_B23_P(rp, j2) \
  b23[j2][0] = *(const bf16x8*)((rp) + ((2 + (j2)) * 16) * 64 + swk0); \
  b23[j2][1] = *(const bf16x8*)((rp) + ((2 + (j2)) * 16) * 64 + swk1);

#define MF4(i0, j0, A, B, i2) \
  acc[(i0)+(i2)][(j0)+0] = __builtin_amdgcn_mfma_f32_16x16x32_bf16(A[i2][0], B[0][0], acc[(i0)+(i2)][(j0)+0], 0, 0, 0); \
  acc[(i0)+(i2)][(j0)+0] = __builtin_amdgcn_mfma_f32_16x16x32_bf16(A[i2][1], B[0][1], acc[(i0)+(i2)][(j0)+0], 0, 0, 0); \
  acc[(i0)+(i2)][(j0)+1] = __builtin_amdgcn_mfma_f32_16x16x32_bf16(A[i2][0], B[1][0], acc[(i0)+(i2)][(j0)+1], 0, 0, 0); \
  acc[(i0)+(i2)][(j0)+1] = __builtin_amdgcn_mfma_f32_16x16x32_bf16(A[i2][1], B[1][1], acc[(i0)+(i2)][(j0)+1], 0, 0, 0);

// 16 MFMAs with three read-hooks pinned between groups of 4
#define MFQ_H(i0, j0, A, B, H1, H2, H3) do { \
  __builtin_amdgcn_s_setprio(1); \
  MF4(i0, j0, A, B, 0) SB0(); H1 SB0(); \
  MF4(i0, j0, A, B, 1) SB0(); H2 SB0(); \
  MF4(i0, j0, A, B, 2) SB0(); H3 SB0(); \
  MF4(i0, j0, A, B, 3) \
  __builtin_amdgcn_s_setprio(0); } while (0)

#define MFQ(i0, j0, A, B) MFQ_H(i0, j0, A, B, , , )

__global__ __launch_bounds__(512, 2) void gemm_gn_min(
    const bf16* __restrict__ xb, const bf16* __restrict__ wb,
    const float* __restrict__ bgemm, float* __restrict__ pmin) {
  __shared__ bf16 sA[32768];   // [2][256*64] W tiles (A-operand), 64 KiB
  __shared__ bf16 sB[32768];   // [2][256*64] x tiles (B-operand), 64 KiB

  const int tid  = threadIdx.x;
  const int lane = tid & 63;
  const int wid  = tid >> 6;      // 0..7
  const int wr   = wid >> 2;      // n-half (0..1): rows wr*128..+127
  const int wc   = wid & 3;       // m-quarter (0..3): cols wc*64..+63
  const int q    = lane >> 4;     // quad 0..3
  const int c    = lane & 15;

  const int mTile = blockIdx.x & (NT_M - 1);
  const int nTile = blockIdx.x >> 5;
  const int mBase = mTile * BT;
  const int nBase = nTile * BT;

  // staging map: lane -> (row-in-8-chunk, xor-swizzled k-chunk on GLOBAL col)
  const int ldRow = lane >> 3;
  const int swz   = ((lane & 7) ^ ldRow) * 8;
  // read-side swizzle (chunk = (ks*4+q) ^ (row&7); row&7 == c&7 here)
  const int swk0 = (q ^ (c & 7)) * 8;
  const int swk1 = ((4 + q) ^ (c & 7)) * 8;

  // per-wave global staging bases (wave covers rows wid*16 + ldRow + {0,8})
  const bf16* gA = wb + (size_t)(nBase + wid * 16 + ldRow) * K_DIM + swz;
  const bf16* gB = xb + (size_t)(mBase + wid * 16 + ldRow) * K_DIM + swz;
  // per-wave LDS dest bases (buf0); buf1 = +16384 elems
  bf16* dA = sA + wid * 1024;
  bf16* dB = sB + wid * 1024;
  // per-lane LDS read bases
  const bf16* rA0 = sA + (wr * 128 + c) * 64;
  const bf16* rA1 = rA0 + 16384;
  const bf16* rB0 = sB + (wc * 64 + c) * 64;
  const bf16* rB1 = rB0 + 16384;

  floatx4 acc[8][4];
#pragma unroll
  for (int i = 0; i < 8; ++i)
#pragma unroll
    for (int j = 0; j < 4; ++j) acc[i][j] = (floatx4){0.f, 0.f, 0.f, 0.f};

  // frag banks; every phase's hook banks are disjoint from its MFMA operands
  bf16x8 af0[4][2], af1[4][2], b01a[2][2], b01b[2][2], b23[2][2];

  // ---- prologue: stage k0 full + k1.B; confirm k0; read k0 frags (16 reads)
  STG2(gB, 0, 0, dB); STG2(gB, 0, 1, dB);                   // k0.B
  STG2(gA, 0, 0, dA); STG2(gA, 0, 1, dA);                   // k0.A
  STG2(gB, 1, 0, dB + 16384); STG2(gB, 1, 1, dB + 16384);   // k1.B
  VMW("4");            // confirms k0 (8 loads); k1.B (4) stays in flight
  BARX();
  RD_A0_P(rA0, 0) RD_A0_P(rA0, 1) RD_A0_P(rA0, 2) RD_A0_P(rA0, 3)
  RD_B01_P(rB0, b01a)
  RD_B23_P(rB0, 0) RD_B23_P(rB0, 1)
  SB0();

  // ---- main loop: iter computes k0=2i (buf0) and k1=2i+1 (buf1).
  // Staging bodies: p1:k1.A  p4:k2.B  p5:k2.A  p8:k3.B (k3.A spills to next
  // iter's p1). vmcnt(0) at p3/p7 retires loads issued 2 phases earlier.
  // Hooks (reads inside MFMA cluster, consumed 2 phases later):
  //  p1:af1(k0) p3:af0(k1)+b01b p4:b23(k1) p5:af1(k1) p7:af0(k2)+b01a p8:b23(k2)
#pragma unroll 1
  for (int i = 0; i < NKT / 2 - 1; ++i) {
    const int k1 = 2 * i + 1, k2 = 2 * i + 2, k3 = 2 * i + 3;
    // p1
    STG2(gA, k1, 0, dA + 16384); STG2(gA, k1, 1, dA + 16384); SB0();
    BARX(); LGKMW("4");
    MFQ_H(0, 0, af0, b01a, RD_A1_P(rA0, 0) RD_A1_P(rA0, 1),
                           RD_A1_P(rA0, 2) RD_A1_P(rA0, 3), );
    // p2
    BARX(); LGKMW("8");
    MFQ(0, 2, af0, b23);
    // p3: confirm k1 fully staged, then read its first frags in hooks
    VMW("0");
    BARX(); LGKMW("0");
    MFQ_H(4, 2, af1, b23, RD_A0_P(rA1, 0) RD_A0_P(rA1, 1),
                          RD_A0_P(rA1, 2) RD_A0_P(rA1, 3),
                          RD_B01_P(rB1, b01b));
    // p4
    STG2(gB, k2, 0, dB); STG2(gB, k2, 1, dB); SB0();
    BARX();
    MFQ_H(4, 0, af1, b01a, RD_B23_P(rB1, 0), RD_B23_P(rB1, 1), );
    // p5
    STG2(gA, k2, 0, dA); STG2(gA, k2, 1, dA); SB0();
    BARX(); LGKMW("4");
    MFQ_H(0, 0, af0, b01b, RD_A1_P(rA1, 0) RD_A1_P(rA1, 1),
                           RD_A1_P(rA1, 2) RD_A1_P(rA1, 3), );
    // p6
    BARX(); LGKMW("8");
    MFQ(0, 2, af0, b23);
    // p7: confirm k2 fully staged
    VMW("0");
    BARX(); LGKMW("0");
    MFQ_H(4, 2, af1, b23, RD_A0_P(rA0, 0) RD_A0_P(rA0, 1),
                          RD_A0_P(rA0, 2) RD_A0_P(rA0, 3),
                          RD_B01_P(rB0, b01a));
    // p8
    STG2(gB, k3, 0, dB + 16384); STG2(gB, k3, 1, dB + 16384); SB0();
    BARX();
    MFQ_H(4, 0, af1, b01b, RD_B23_P(rB0, 0), RD_B23_P(rB0, 1), );
  }

  // ---- epilogue: tiles 30 (buf0) / 31 (buf1); stage k31.A at e1; no k2/k3
  // e1
  STG2(gA, NKT - 1, 0, dA + 16384); STG2(gA, NKT - 1, 1, dA + 16384); SB0();
  BARX(); LGKMW("4");
  MFQ_H(0, 0, af0, b01a, RD_A1_P(rA0, 0) RD_A1_P(rA0, 1),
                         RD_A1_P(rA0, 2) RD_A1_P(rA0, 3), );
  // e2
  BARX(); LGKMW("8");
  MFQ(0, 2, af0, b23);
  // e3: drain staging (k31 fully)
  VMW("0");
  BARX(); LGKMW("0");
  MFQ_H(4, 2, af1, b23, RD_A0_P(rA1, 0) RD_A0_P(rA1, 1),
                        RD_A0_P(rA1, 2) RD_A0_P(rA1, 3),
                        RD_B01_P(rB1, b01b));
  // e4
  BARX();
  MFQ_H(4, 0, af1, b01a, RD_B23_P(rB1, 0), RD_B23_P(rB1, 1), );
  // e5
  BARX(); LGKMW("4");
  MFQ_H(0, 0, af0, b01b, RD_A1_P(rA1, 0) RD_A1_P(rA1, 1),
                         RD_A1_P(rA1, 2) RD_A1_P(rA1, 3), );
  // e6
  BARX(); LGKMW("8");
  MFQ(0, 2, af0, b23);
  // e7
  BARX(); LGKMW("0");
  MFQ(4, 2, af1, b23);
  // e8
  MFQ(4, 0, af1, b01b);

  // ---- fused epilogue: +b, groupnorm over 8 consecutive n, min over n per m
  float colmin[4] = {3.4e38f, 3.4e38f, 3.4e38f, 3.4e38f};
#pragma unroll
  for (int i = 0; i < 8; ++i) {
    const float* bp = bgemm + nBase + wr * 128 + i * 16 + q * 4;
    float b0 = bp[0], b1 = bp[1], b2 = bp[2], b3 = bp[3];
#pragma unroll
    for (int j = 0; j < 4; ++j) {
      float v0 = acc[i][j][0] + b0;
      float v1 = acc[i][j][1] + b1;
      float v2 = acc[i][j][2] + b2;
      float v3 = acc[i][j][3] + b3;
      float s  = (v0 + v1) + (v2 + v3);
      float ss = (v0 * v0 + v1 * v1) + (v2 * v2 + v3 * v3);
      // partner quad (lane^16) holds the other 4 n's of this group of 8
      s  += __shfl_xor(s, 16);
      ss += __shfl_xor(ss, 16);
      float mean = s * 0.125f;
      float var  = ss * 0.125f - mean * mean;
      float inv  = rsqrtf(var + 1e-5f);          // inv > 0, so min commutes
      float mndev = fminf(fminf(v0, v1), fminf(v2, v3)) - mean;
      colmin[j] = fminf(colmin[j], mndev * inv);
    }
  }
#pragma unroll
  for (int j = 0; j < 4; ++j) {
    float m0 = colmin[j];
    m0 = fminf(m0, __shfl_xor(m0, 16));
    m0 = fminf(m0, __shfl_xor(m0, 32));
    colmin[j] = m0;
  }
  // LDS tiles are dead now; reuse the front of sA for the 2x256 partial mins.
  float* sm = (float*)sA;
  __syncthreads();
  if (q == 0) {
#pragma unroll
    for (int j = 0; j < 4; ++j)
      sm[wr * 256 + wc * 64 + j * 16 + c] = colmin[j];
  }
  __syncthreads();
  if (tid < 256) {
    float p = fminf(sm[tid], sm[256 + tid]);
    pmin[(size_t)(mBase + tid) * NT_N + nTile] = p;   // one writer per slot
  }
}

// ---------------- Kernel 2: out[m, n] = rowmin[m] + bias[n] -------------------
__global__ __launch_bounds__(256) void out_kernel(
    const float* __restrict__ pmin, const float* __restrict__ bias,
    float* __restrict__ out) {
  const int m = blockIdx.x;
  const int tid = threadIdx.x;
  __shared__ float srow;
  if (tid < 64) {
    float v = (tid < NT_N) ? pmin[m * NT_N + tid] : 3.4e38f;
    v = fminf(v, __shfl_xor(v, 1));
    v = fminf(v, __shfl_xor(v, 2));
    v = fminf(v, __shfl_xor(v, 4));
    v = fminf(v, __shfl_xor(v, 8));
    v = fminf(v, __shfl_xor(v, 16));
    if (tid == 0) srow = v;
  }
  __syncthreads();
  const float rmin = srow;
  const float4* b4 = (const float4*)bias;
  float4* o4 = (float4*)(out + (size_t)m * N_DIM);
#pragma unroll
  for (int it = 0; it < 4; ++it) {
    int idx2 = it * 256 + tid;
    float4 bb = b4[idx2];
    o4[idx2] = (float4){rmin + bb.x, rmin + bb.y, rmin + bb.z, rmin + bb.w};
  }
}

extern "C" void kernel_launch(void* const* d_in, const int* in_sizes, int n_in,
                              void* d_out, int out_size, void* d_ws, size_t ws_size,
                              hipStream_t stream) {
  const float* x    = (const float*)d_in[0];
  const float* W    = (const float*)d_in[1];
  const float* b    = (const float*)d_in[2];
  const float* bias = (const float*)d_in[3];
  float* out = (float*)d_out;

  // bf16 scratch lives in d_out (134 MB >> 50 MB needed); overwritten at the end.
  bf16* xb = (bf16*)d_out;
  bf16* wb = (bf16*)((char*)d_out + (size_t)M_DIM * K_DIM * sizeof(bf16));
  float* pmin = (float*)d_ws;  // 8192 * 16 * 4 = 512 KiB of workspace

  convert_kernel<<<(M_DIM * K_DIM + N_DIM * K_DIM) / (8 * 256), 256, 0, stream>>>(x, W, xb, wb);
  gemm_gn_min<<<NT_M * NT_N, 512, 0, stream>>>(xb, wb, b, pmin);
  out_kernel<<<M_DIM, 256, 0, stream>>>(pmin, bias, out);
}

// Round 8
// 324.434 us; speedup vs baseline: 1.0725x; 1.0725x over previous
//
#include <hip/hip_runtime.h>
#include <hip/hip_bf16.h>
#include <stdint.h>

#define M_DIM 8192
#define K_DIM 2048
#define N_DIM 4096
#define BT 256
#define NT_M (M_DIM / BT)   // 32 m-tiles
#define NT_N (N_DIM / BT)   // 16 n-tiles
#define NKT (K_DIM / 64)    // 32 K-tiles of BK=64

typedef __hip_bfloat16 bf16;
typedef __attribute__((ext_vector_type(8))) short bf16x8;
typedef __attribute__((ext_vector_type(4))) float floatx4;

__device__ __forceinline__ void gload_lds16(const void* g, void* l) {
  __builtin_amdgcn_global_load_lds((const __attribute__((address_space(1))) void*)g,
                                   (__attribute__((address_space(3))) void*)l, 16, 0, 0);
}

// ---------------- Kernel 0: fp32 -> bf16 convert (x then W), 16 elems/thread --
__global__ __launch_bounds__(256) void convert_kernel(
    const float* __restrict__ x, const float* __restrict__ W,
    bf16* __restrict__ xb, bf16* __restrict__ wb) {
  int idx = blockIdx.x * 256 + threadIdx.x;
  long e = (long)idx * 16;
  const long NX = (long)M_DIM * K_DIM;  // 16,777,216 (divisible by 16)
  const float* src;
  bf16* dst;
  if (e < NX) { src = x + e; dst = xb + e; }
  else        { src = W + (e - NX); dst = wb + (e - NX); }
  const float4* s4 = (const float4*)src;
  float4 a0 = s4[0], a1 = s4[1], a2 = s4[2], a3 = s4[3];
  union { bf16 h[16]; uint4 u[2]; } o;
  o.h[0]  = __float2bfloat16(a0.x); o.h[1]  = __float2bfloat16(a0.y);
  o.h[2]  = __float2bfloat16(a0.z); o.h[3]  = __float2bfloat16(a0.w);
  o.h[4]  = __float2bfloat16(a1.x); o.h[5]  = __float2bfloat16(a1.y);
  o.h[6]  = __float2bfloat16(a1.z); o.h[7]  = __float2bfloat16(a1.w);
  o.h[8]  = __float2bfloat16(a2.x); o.h[9]  = __float2bfloat16(a2.y);
  o.h[10] = __float2bfloat16(a2.z); o.h[11] = __float2bfloat16(a2.w);
  o.h[12] = __float2bfloat16(a3.x); o.h[13] = __float2bfloat16(a3.y);
  o.h[14] = __float2bfloat16(a3.z); o.h[15] = __float2bfloat16(a3.w);
  uint4* d4 = (uint4*)dst;
  d4[0] = o.u[0];
  d4[1] = o.u[1];
}

// ---------------- Kernel 1: 256x256 8-phase pipelined GEMM (C^T) + GN + min ----
// Round-5 BEST (116.5 us, MfmaUtil 50): reads issued BEFORE the phase barrier;
// counted lgkm waits; vmcnt(2) at p4/p8 only; A-halves staged at p2/p6 so the
// tightest staging->vmcnt margin is 2 MFMA-phases (~1240 cyc > ~900 cyc HBM).

#define BARX() __builtin_amdgcn_s_barrier()
#define SB0()  __builtin_amdgcn_sched_barrier(0)
#define LGKMW(n) do { asm volatile("s_waitcnt lgkmcnt(" n ")" ::: "memory"); \
                      __builtin_amdgcn_sched_barrier(0); } while (0)
#define VMW(n)   do { asm volatile("s_waitcnt vmcnt(" n ")" ::: "memory"); \
                      __builtin_amdgcn_sched_barrier(0); } while (0)

// stage one half-tile (128 rows x 64 k) of one matrix: 2 gload_lds per wave
#define STG2(gp, kt, hh, dp) do { \
  gload_lds16((gp) + ((hh) * 128 + 0) * K_DIM + (kt) * 64, (void*)((dp) + (hh) * 8192)); \
  gload_lds16((gp) + ((hh) * 128 + 8) * K_DIM + (kt) * 64, (void*)((dp) + (hh) * 8192 + 512)); \
} while (0)

// frag reads (8-per A-half, 4-per B-pair); swk* carries the XOR bank swizzle
#define RD_A0(rp) do { _Pragma("unroll") for (int i2 = 0; i2 < 4; ++i2) { \
  af0[i2][0] = *(const bf16x8*)((rp) + (i2 * 16) * 64 + swk0); \
  af0[i2][1] = *(const bf16x8*)((rp) + (i2 * 16) * 64 + swk1); } } while (0)
#define RD_A1(rp) do { _Pragma("unroll") for (int i2 = 0; i2 < 4; ++i2) { \
  af1[i2][0] = *(const bf16x8*)((rp) + (64 + i2 * 16) * 64 + swk0); \
  af1[i2][1] = *(const bf16x8*)((rp) + (64 + i2 * 16) * 64 + swk1); } } while (0)
#define RD_B01(rp, B) do { _Pragma("unroll") for (int j2 = 0; j2 < 2; ++j2) { \
  B[j2][0] = *(const bf16x8*)((rp) + (j2 * 16) * 64 + swk0); \
  B[j2][1] = *(const bf16x8*)((rp) + (j2 * 16) * 64 + swk1); } } while (0)
#define RD_B23(rp) do { _Pragma("unroll") for (int j2 = 0; j2 < 2; ++j2) { \
  b23[j2][0] = *(const bf16x8*)((rp) + ((2 + j2) * 16) * 64 + swk0); \
  b23[j2][1] = *(const bf16x8*)((rp) + ((2 + j2) * 16) * 64 + swk1); } } while (0)

#define MFQ(i0, j0, A, B) do { \
  __builtin_amdgcn_s_setprio(1); \
  _Pragma("unroll") for (int i2 = 0; i2 < 4; ++i2) \
  _Pragma("unroll") for (int j2 = 0; j2 < 2; ++j2) { \
    acc[(i0) + i2][(j0) + j2] = __builtin_amdgcn_mfma_f32_16x16x32_bf16( \
        A[i2][0], B[j2][0], acc[(i0) + i2][(j0) + j2], 0, 0, 0); \
    acc[(i0) + i2][(j0) + j2] = __builtin_amdgcn_mfma_f32_16x16x32_bf16( \
        A[i2][1], B[j2][1], acc[(i0) + i2][(j0) + j2], 0, 0, 0); } \
  __builtin_amdgcn_s_setprio(0); } while (0)

__global__ __launch_bounds__(512, 2) void gemm_gn_min(
    const bf16* __restrict__ xb, const bf16* __restrict__ wb,
    const float* __restrict__ bgemm, float* __restrict__ pmin) {
  __shared__ bf16 sA[32768];   // [2][256*64] W tiles (A-operand), 64 KiB
  __shared__ bf16 sB[32768];   // [2][256*64] x tiles (B-operand), 64 KiB

  const int tid  = threadIdx.x;
  const int lane = tid & 63;
  const int wid  = tid >> 6;      // 0..7
  const int wr   = wid >> 2;      // n-half (0..1): rows wr*128..+127
  const int wc   = wid & 3;       // m-quarter (0..3): cols wc*64..+63
  const int q    = lane >> 4;     // quad 0..3
  const int c    = lane & 15;

  const int mTile = blockIdx.x & (NT_M - 1);
  const int nTile = blockIdx.x >> 5;
  const int mBase = mTile * BT;
  const int nBase = nTile * BT;

  // staging map: lane -> (row-in-8-chunk, xor-swizzled k-chunk on GLOBAL col)
  const int ldRow = lane >> 3;
  const int swz   = ((lane & 7) ^ ldRow) * 8;
  // read-side swizzle (chunk = (ks*4+q) ^ (row&7); row&7 == c&7 here)
  const int swk0 = (q ^ (c & 7)) * 8;
  const int swk1 = ((4 + q) ^ (c & 7)) * 8;

  // per-wave global staging bases (wave covers rows wid*16 + ldRow + {0,8})
  const bf16* gA = wb + (size_t)(nBase + wid * 16 + ldRow) * K_DIM + swz;
  const bf16* gB = xb + (size_t)(mBase + wid * 16 + ldRow) * K_DIM + swz;
  // per-wave LDS dest bases (buf0); buf1 = +16384 elems
  bf16* dA = sA + wid * 1024;
  bf16* dB = sB + wid * 1024;
  // per-lane LDS read bases
  const bf16* rA0 = sA + (wr * 128 + c) * 64;
  const bf16* rA1 = rA0 + 16384;
  const bf16* rB0 = sB + (wc * 64 + c) * 64;
  const bf16* rB1 = rB0 + 16384;

  floatx4 acc[8][4];
#pragma unroll
  for (int i = 0; i < 8; ++i)
#pragma unroll
    for (int j = 0; j < 4; ++j) acc[i][j] = (floatx4){0.f, 0.f, 0.f, 0.f};

  // frag register banks. af0/af1: A-halves of current K-tile. b01a/b01b:
  // alternating banks for B rows 0-31. b23: single bank.
  bf16x8 af0[4][2], af1[4][2], b01a[2][2], b01b[2][2], b23[2][2];

  // ---- prologue: tile 0 full + tile 1 B-half0; 2 staging instrs stay in flight
  STG2(gB, 0, 0, dB); STG2(gB, 0, 1, dB);
  STG2(gA, 0, 0, dA); STG2(gA, 0, 1, dA);
  STG2(gB, 1, 0, dB + 16384);
  VMW("2");
  BARX();
  RD_A0(rA0); RD_B01(rB0, b01a); SB0();

  // ---- main loop: iter i computes K-tiles 2i (buf0, p1-4) and 2i+1 (buf1,
  // p5-8). Staging: p1:b1.Bh1<-k1 p2:b1.Ah0+b1.Ah1<-k1 p3:- p4:b0.Bh0<-k2
  // p5:b0.Bh1 p6:b0.Ah0+b0.Ah1 p7:- p8:b1.Bh0<-k3. vmcnt(2) at p4/p8 only;
  // tightest margin 2 phases (Ah1 staged p2, confirmed p4). Each body
  // issues next phase's frags; wait lgkmcnt(#issued) after the barrier.
#pragma unroll 1
  for (int i = 0; i < NKT / 2 - 1; ++i) {
    const int k1 = 2 * i + 1, k2 = 2 * i + 2, k3 = 2 * i + 3;
    // p1
    RD_B23(rB0); SB0();
    STG2(gB, k1, 1, dB + 16384); SB0();
    BARX(); LGKMW("4"); MFQ(0, 0, af0, b01a);
    // p2: stage BOTH A-halves of k1 (margin 2 at p4's vmcnt)
    RD_A1(rA0); SB0();
    STG2(gA, k1, 0, dA + 16384); STG2(gA, k1, 1, dA + 16384); SB0();
    BARX(); LGKMW("8"); MFQ(0, 2, af0, b23);
    // p3: no staging
    BARX(); LGKMW("0"); MFQ(4, 2, af1, b23);
    // p4: rendezvous for buf1 (tile k1) readiness, then cross-buffer read-ahead
    STG2(gB, k2, 0, dB); VMW("2");
    BARX();
    RD_A0(rA1); RD_B01(rB1, b01b); SB0();
    MFQ(4, 0, af1, b01a);
    // p5
    RD_B23(rB1); SB0();
    STG2(gB, k2, 1, dB); SB0();
    BARX(); LGKMW("4"); MFQ(0, 0, af0, b01b);
    // p6: stage BOTH A-halves of k2
    RD_A1(rA1); SB0();
    STG2(gA, k2, 0, dA); STG2(gA, k2, 1, dA); SB0();
    BARX(); LGKMW("8"); MFQ(0, 2, af0, b23);
    // p7: no staging
    BARX(); LGKMW("0"); MFQ(4, 2, af1, b23);
    // p8: rendezvous for buf0 (tile k2) readiness
    STG2(gB, k3, 0, dB + 16384); VMW("2");
    BARX();
    RD_A0(rA0); RD_B01(rB0, b01a); SB0();
    MFQ(4, 0, af1, b01b);
  }

  // ---- epilogue: tiles 30 (buf0) and 31 (buf1); drain staging at e4
  // e1
  RD_B23(rB0); SB0();
  STG2(gB, NKT - 1, 1, dB + 16384); SB0();
  BARX(); LGKMW("4"); MFQ(0, 0, af0, b01a);
  // e2: stage BOTH A-halves of tile 31
  RD_A1(rA0); SB0();
  STG2(gA, NKT - 1, 0, dA + 16384); STG2(gA, NKT - 1, 1, dA + 16384); SB0();
  BARX(); LGKMW("8"); MFQ(0, 2, af0, b23);
  // e3: no staging
  BARX(); LGKMW("0"); MFQ(4, 2, af1, b23);
  // e4: all outstanding staging instrs belong to tile 31 -> drain fully
  VMW("0");
  BARX();
  RD_A0(rA1); RD_B01(rB1, b01b); SB0();
  MFQ(4, 0, af1, b01a);
  // e5
  RD_B23(rB1); SB0();
  BARX(); LGKMW("4"); MFQ(0, 0, af0, b01b);
  // e6
  RD_A1(rA1); SB0();
  BARX(); LGKMW("8"); MFQ(0, 2, af0, b23);
  // e7
  BARX(); LGKMW("0"); MFQ(4, 2, af1, b23);
  // e8
  MFQ(4, 0, af1, b01b);

  // ---- fused epilogue: +b, groupnorm over 8 consecutive n, min over n per m
  float colmin[4] = {3.4e38f, 3.4e38f, 3.4e38f, 3.4e38f};
#pragma unroll
  for (int i = 0; i < 8; ++i) {
    const float* bp = bgemm + nBase + wr * 128 + i * 16 + q * 4;
    float b0 = bp[0], b1 = bp[1], b2 = bp[2], b3 = bp[3];
#pragma unroll
    for (int j = 0; j < 4; ++j) {
      float v0 = acc[i][j][0] + b0;
      float v1 = acc[i][j][1] + b1;
      float v2 = acc[i][j][2] + b2;
      float v3 = acc[i][j][3] + b3;
      float s  = (v0 + v1) + (v2 + v3);
      float ss = (v0 * v0 + v1 * v1) + (v2 * v2 + v3 * v3);
      // partner quad (lane^16) holds the other 4 n's of this group of 8
      s  += __shfl_xor(s, 16);
      ss += __shfl_xor(ss, 16);
      float mean = s * 0.125f;
      float var  = ss * 0.125f - mean * mean;
      float inv  = rsqrtf(var + 1e-5f);          // inv > 0, so min commutes
      float mndev = fminf(fminf(v0, v1), fminf(v2, v3)) - mean;
      colmin[j] = fminf(colmin[j], mndev * inv);
    }
  }
#pragma unroll
  for (int j = 0; j < 4; ++j) {
    float m0 = colmin[j];
    m0 = fminf(m0, __shfl_xor(m0, 16));
    m0 = fminf(m0, __shfl_xor(m0, 32));
    colmin[j] = m0;
  }
  // LDS tiles are dead now; reuse the front of sA for the 2x256 partial mins.
  float* sm = (float*)sA;
  __syncthreads();
  if (q == 0) {
#pragma unroll
    for (int j = 0; j < 4; ++j)
      sm[wr * 256 + wc * 64 + j * 16 + c] = colmin[j];
  }
  __syncthreads();
  if (tid < 256) {
    float p = fminf(sm[tid], sm[256 + tid]);
    pmin[(size_t)(mBase + tid) * NT_N + nTile] = p;   // one writer per slot
  }
}

// ---------------- Kernel 2: out[m, n] = rowmin[m] + bias[n] -------------------
// One wave per row (4 rows/block, 2048 blocks); no LDS/sync; nontemporal
// stores (via native clang vector type) for the 128 MB write-only stream.
__global__ __launch_bounds__(256) void out_kernel(
    const float* __restrict__ pmin, const float* __restrict__ bias,
    float* __restrict__ out) {
  const int wv   = threadIdx.x >> 6;
  const int lane = threadIdx.x & 63;
  const int m = blockIdx.x * 4 + wv;
  float v = (lane < NT_N) ? pmin[(size_t)m * NT_N + lane] : 3.4e38f;
  v = fminf(v, __shfl_xor(v, 1));
  v = fminf(v, __shfl_xor(v, 2));
  v = fminf(v, __shfl_xor(v, 4));
  v = fminf(v, __shfl_xor(v, 8));
  const float rmin = __shfl(v, 0);
  const floatx4* b4 = (const floatx4*)bias;
  floatx4* o4 = (floatx4*)(out + (size_t)m * N_DIM);
#pragma unroll
  for (int it = 0; it < 16; ++it) {
    int idx2 = it * 64 + lane;
    floatx4 bb = b4[idx2];
    floatx4 ov = bb + rmin;
    __builtin_nontemporal_store(ov, &o4[idx2]);
  }
}

extern "C" void kernel_launch(void* const* d_in, const int* in_sizes, int n_in,
                              void* d_out, int out_size, void* d_ws, size_t ws_size,
                              hipStream_t stream) {
  const float* x    = (const float*)d_in[0];
  const float* W    = (const float*)d_in[1];
  const float* b    = (const float*)d_in[2];
  const float* bias = (const float*)d_in[3];
  float* out = (float*)d_out;

  // bf16 scratch lives in d_out (134 MB >> 50 MB needed); overwritten at the end.
  bf16* xb = (bf16*)d_out;
  bf16* wb = (bf16*)((char*)d_out + (size_t)M_DIM * K_DIM * sizeof(bf16));
  float* pmin = (float*)d_ws;  // 8192 * 16 * 4 = 512 KiB of workspace

  convert_kernel<<<(M_DIM * K_DIM + N_DIM * K_DIM) / (16 * 256), 256, 0, stream>>>(x, W, xb, wb);
  gemm_gn_min<<<NT_M * NT_N, 512, 0, stream>>>(xb, wb, b, pmin);
  out_kernel<<<M_DIM / 4, 256, 0, stream>>>(pmin, bias, out);
}